// Round 1
// 414.192 us; speedup vs baseline: 1.0163x; 1.0163x over previous
//
#include <hip/hip_runtime.h>
#include <hip/hip_bf16.h>

typedef unsigned short u16b;                                   // raw bf16 bits
typedef __attribute__((ext_vector_type(8))) short short8;      // 8 bf16 = 4 VGPR (MFMA A/B frag)
typedef __attribute__((ext_vector_type(4))) float floatx4;     // MFMA C/D frag

#define DEV static __device__ __forceinline__

DEV float sh2f(unsigned short s) { union { unsigned u; float f; } c; c.u = ((unsigned)s) << 16; return c.f; }
DEV unsigned short f2b(float f) {
    unsigned u = __float_as_uint(f);
    u += 0x7FFF + ((u >> 16) & 1);      // RNE to bf16
    return (unsigned short)(u >> 16);
}

// packed small-vector offsets (elements) — shared host/device
constexpr int O_LN1G = 0, O_LN1B = 256, O_QB = 512, O_KB = 768, O_VB = 1024,
              O_TB = 1280, O_PB = 1536, O_FFNG = 1792, O_FFNB = 2048,
              O_B1 = 2304, O_B2 = 2560, O_QAB = 2816, O_KAB = 2824,
              O_QAW = 2832, O_KAW = 4880, O_CV = 6928;

// ---------------------------------------------------------------------------
// Input dtype sniffer. flag[0] = 1 -> inputs are fp32;  0 -> bf16.
// ---------------------------------------------------------------------------
__global__ void detect_k(const unsigned* __restrict__ xw, int* __restrict__ flag) {
    __shared__ int cnt;
    if (threadIdx.x == 0) cnt = 0;
    __syncthreads();
    int my = 0;
    for (int i = threadIdx.x; i < 4096; i += 256) {
        unsigned w = xw[i];
        unsigned e0 = (w >> 7) & 0xFFu;      // low half's bf16 exponent
        if (e0 >= 0xC0u) my++;
    }
    atomicAdd(&cnt, my);
    __syncthreads();
    if (threadIdx.x == 0) flag[0] = (cnt > 64) ? 1 : 0;
}

DEV unsigned short load_cvt(const void* src, size_t idx, int fp32) {
    return fp32 ? f2b(((const float*)src)[idx]) : ((const u16b*)src)[idx];
}

// ---------------------------------------------------------------------------
// Pack + convert the small vectors (gains/biases/qa/ka) into sv (bf16).
// ---------------------------------------------------------------------------
struct VecTab { const void* p[15]; int off[15]; int n[15]; };

__global__ __launch_bounds__(256)
void convert_vecs_k(VecTab tab, const int* __restrict__ flag, u16b* __restrict__ sv) {
    int e = blockIdx.x, fp32 = flag[0];
    const void* s = tab.p[e];
    int n = tab.n[e], off = tab.off[e];
    for (int i = threadIdx.x; i < n; i += 256)
        sv[off + i] = load_cvt(s, i, fp32);
}

// ---------------------------------------------------------------------------
// Batched 256x256 weight transpose: 8 slices, per-slice dst offset + row stride.
// dst[c * rstride + r] = src[r, c]
// ---------------------------------------------------------------------------
struct W8 { const void* p[8]; unsigned dstoff[8]; unsigned rstride[8]; };

__global__ void wtrans_k(W8 tab, u16b* __restrict__ base, const int* __restrict__ flag) {
    __shared__ u16b tile[32][33];
    int fp32 = flag[0];
    const void* src = tab.p[blockIdx.z];
    u16b* dst = base + tab.dstoff[blockIdx.z];
    unsigned rs = tab.rstride[blockIdx.z];
    int c0 = blockIdx.x * 32, r0 = blockIdx.y * 32;
    int tx = threadIdx.x, ty = threadIdx.y;
#pragma unroll
    for (int i = 0; i < 32; i += 8)
        tile[ty + i][tx] = load_cvt(src, (size_t)(r0 + ty + i) * 256 + c0 + tx, fp32);
    __syncthreads();
#pragma unroll
    for (int i = 0; i < 32; i += 8)
        dst[(size_t)(c0 + ty + i) * rs + r0 + tx] = tile[tx][ty + i];
}

// ---------------------------------------------------------------------------
// dtype-converting x transpose in, y transpose out — wide-IO (G13):
// 4 elems/lane on both global sides (8-16 B/lane instead of 2-4 B scalar).
// ---------------------------------------------------------------------------
__global__ __launch_bounds__(256)
void transpose_in_k(const void* __restrict__ src, u16b* __restrict__ dst,
                    int rows, int cols, const int* __restrict__ flag) {
    __shared__ u16b tile[32][36];
    int fp32 = flag[0];
    int c0 = blockIdx.x * 32, r0 = blockIdx.y * 32;
    size_t zb = (size_t)blockIdx.z * rows * cols;
    int tid = threadIdx.x;
    int r = tid >> 3, c4 = (tid & 7) * 4;
    size_t sidx = zb + (size_t)(r0 + r) * cols + c0 + c4;
    if (fp32) {
        const float4 f4 = *(const float4*)((const float*)src + sidx);
        tile[r][c4]     = f2b(f4.x);
        tile[r][c4 + 1] = f2b(f4.y);
        tile[r][c4 + 2] = f2b(f4.z);
        tile[r][c4 + 3] = f2b(f4.w);
    } else {
        *(ushort4*)&tile[r][c4] = *(const ushort4*)((const u16b*)src + sidx);
    }
    __syncthreads();
    int c = tid >> 3, r4 = (tid & 7) * 4;
    ushort4 o;
    o.x = tile[r4][c]; o.y = tile[r4 + 1][c]; o.z = tile[r4 + 2][c]; o.w = tile[r4 + 3][c];
    *(ushort4*)&dst[zb + (size_t)(c0 + c) * rows + r0 + r4] = o;
}

__global__ __launch_bounds__(256)
void transpose_out_k(const u16b* __restrict__ src, void* __restrict__ dst,
                     int rows, int cols, const int* __restrict__ flag) {
    __shared__ u16b tile[32][36];
    int fp32 = flag[0];
    int c0 = blockIdx.x * 32, r0 = blockIdx.y * 32;
    size_t zb = (size_t)blockIdx.z * rows * cols;
    int tid = threadIdx.x;
    int r = tid >> 3, c4 = (tid & 7) * 4;
    *(ushort4*)&tile[r][c4] = *(const ushort4*)&src[zb + (size_t)(r0 + r) * cols + c0 + c4];
    __syncthreads();
    int c = tid >> 3, r4 = (tid & 7) * 4;
    size_t didx = zb + (size_t)(c0 + c) * rows + r0 + r4;
    if (fp32) {
        float4 f4;
        f4.x = sh2f(tile[r4][c]);     f4.y = sh2f(tile[r4 + 1][c]);
        f4.z = sh2f(tile[r4 + 2][c]); f4.w = sh2f(tile[r4 + 3][c]);
        *(float4*)((float*)dst + didx) = f4;
    } else {
        ushort4 o;
        o.x = tile[r4][c]; o.y = tile[r4 + 1][c]; o.z = tile[r4 + 2][c]; o.w = tile[r4 + 3][c];
        *(ushort4*)((u16b*)dst + didx) = o;
    }
}

// ---------------------------------------------------------------------------
// Per-row LN stats (mean, rstd) over C=256. One wave per row, 4 rows/block.
// Rows >= valid get (0,0): downstream inline-LN then yields the bias vector.
// ---------------------------------------------------------------------------
__global__ __launch_bounds__(256)
void rowstats_k(const u16b* __restrict__ src, float2* __restrict__ st,
                int valid, int total) {
    int wv = threadIdx.x >> 6, lane = threadIdx.x & 63;
    int r = blockIdx.x * 4 + wv;
    if (r >= total) return;
    if (r >= valid) { if (lane == 0) st[r] = make_float2(0.f, 0.f); return; }
    int c = lane * 4;
    ushort4 raw = *(const ushort4*)&src[(size_t)r * 256 + c];
    float x0 = sh2f(raw.x), x1 = sh2f(raw.y), x2 = sh2f(raw.z), x3 = sh2f(raw.w);
    float s  = x0 + x1 + x2 + x3;
    float sq = x0 * x0 + x1 * x1 + x2 * x2 + x3 * x3;
#pragma unroll
    for (int o = 32; o; o >>= 1) { s += __shfl_xor(s, o); sq += __shfl_xor(sq, o); }
    float mean = s * (1.f / 256.f);
    float var  = sq * (1.f / 256.f) - mean * mean;
    if (lane == 0) st[r] = make_float2(mean, rsqrtf(var + 1e-5f));
}

// ---------------------------------------------------------------------------
// cvec[j] = t_b @ p_w[:, j] + p_b[j]  via pT rows (contiguous dot). 1 block.
// ---------------------------------------------------------------------------
__global__ __launch_bounds__(256)
void cvec_k(const u16b* __restrict__ pT, u16b* __restrict__ sv) {
    int j = threadIdx.x;
    float acc = sh2f(sv[O_PB + j]);
    const u16b* row = pT + (size_t)j * 256;
    for (int i = 0; i < 256; i += 8) {
        short8 t8 = *(const short8*)&sv[O_TB + i];
        short8 p8 = *(const short8*)&row[i];
#pragma unroll
        for (int u = 0; u < 8; ++u)
            acc += sh2f((unsigned short)t8[u]) * sh2f((unsigned short)p8[u]);
    }
    sv[O_CV + j] = f2b(acc);
}

// ---------------------------------------------------------------------------
// bf16 GEMM: out[M x N] = A[M x K] @ W (Wt is N x K) + epilogue.
// LNA=1: apply LayerNorm (stats + gvec/bvec) to A rows during LDS staging (K==256).
// EPI: 0 = +bias (out stride osParam); 2 = +bias +addm (stride 256);
//      3 = gelu(acc+bias); 4 = +bias tri-split: out[(col>>8)*osParam + row*256 + (col&255)]
// ---------------------------------------------------------------------------
template <int EPI, int LNA>
__global__ __launch_bounds__(256)
void gemm256(const u16b* __restrict__ A, int aStride, int K,
             const u16b* __restrict__ Wt,
             const u16b* __restrict__ bias, const u16b* __restrict__ addm,
             u16b* __restrict__ out, size_t osParam,
             const float2* __restrict__ stats,
             const u16b* __restrict__ gvec, const u16b* __restrict__ bvec) {
    __shared__ u16b As[128 * 72];
    __shared__ u16b Bs[128 * 72];
    __shared__ float sg[256], sb[256];
    const int tid = threadIdx.x;
    const int m0 = blockIdx.x * 128, n0 = blockIdx.y * 128;
    const int wv = tid >> 6, lane = tid & 63;
    const int wrow = (wv >> 1) * 64, wcol = (wv & 1) * 64;
    const int fr = lane & 15;            // frag row (m for A, n for B), also C col
    const int fq = lane >> 4;            // quad: k offset fq*8; C row offset fq*4
    floatx4 acc[4][4];
    const floatx4 zero = {0.f, 0.f, 0.f, 0.f};
#pragma unroll
    for (int i = 0; i < 4; ++i)
#pragma unroll
        for (int j = 0; j < 4; ++j) acc[i][j] = zero;

    float2 strow[4];
    if (LNA) {
        sg[tid] = sh2f(gvec[tid]);
        sb[tid] = sh2f(bvec[tid]);
#pragma unroll
        for (int kk = 0; kk < 4; ++kk) strow[kk] = stats[m0 + (tid >> 3) + kk * 32];
        __syncthreads();
    }

    for (int kt = 0; kt < K; kt += 64) {
#pragma unroll
        for (int kk = 0; kk < 4; ++kk) {
            int chunk = tid + kk * 256;              // 1024 chunks of 8 elems
            int row = chunk >> 3, col = (chunk & 7) * 8;
            union { uint4 u; unsigned short h[8]; } rw;
            rw.u = *(const uint4*)&A[(size_t)(m0 + row) * aStride + kt + col];
            if (LNA) {
#pragma unroll
                for (int j = 0; j < 8; ++j) {
                    float f = sh2f(rw.h[j]);
                    f = (f - strow[kk].x) * strow[kk].y * sg[kt + col + j] + sb[kt + col + j];
                    rw.h[j] = f2b(f);
                }
            }
            *(uint4*)&As[row * 72 + col] = rw.u;
            *(uint4*)&Bs[row * 72 + col] = *(const uint4*)&Wt[(size_t)(n0 + row) * K + kt + col];
        }
        __syncthreads();
#pragma unroll
        for (int s = 0; s < 2; ++s) {
            short8 af[4], bfr[4];
#pragma unroll
            for (int i = 0; i < 4; ++i)
                af[i] = *(short8*)&As[(wrow + i * 16 + fr) * 72 + s * 32 + fq * 8];
#pragma unroll
            for (int j = 0; j < 4; ++j)
                bfr[j] = *(short8*)&Bs[(wcol + j * 16 + fr) * 72 + s * 32 + fq * 8];
#pragma unroll
            for (int i = 0; i < 4; ++i)
#pragma unroll
                for (int j = 0; j < 4; ++j)
                    acc[i][j] = __builtin_amdgcn_mfma_f32_16x16x32_bf16(af[i], bfr[j], acc[i][j], 0, 0, 0);
        }
        __syncthreads();
    }
    // epilogue; C/D layout: col = lane&15, row = (lane>>4)*4 + reg
    float bv[4];
#pragma unroll
    for (int j = 0; j < 4; ++j) bv[j] = bias ? sh2f(bias[n0 + wcol + j * 16 + fr]) : 0.f;
#pragma unroll
    for (int i = 0; i < 4; ++i) {
#pragma unroll
        for (int r = 0; r < 4; ++r) {
            int row = m0 + wrow + i * 16 + fq * 4 + r;
            size_t ro = (size_t)row * 256;
#pragma unroll
            for (int j = 0; j < 4; ++j) {
                int col = n0 + wcol + j * 16 + fr;
                float val = acc[i][j][r] + bv[j];
                if (EPI == 2) val += sh2f(addm[ro + col]);
                if (EPI == 3) val = 0.5f * val * (1.0f + erff(val * 0.70710678118654752f));
                if (EPI == 4)      out[(size_t)(col >> 8) * osParam + ro + (col & 255)] = f2b(val);
                else if (EPI == 0) out[(size_t)row * osParam + col] = f2b(val);
                else               out[ro + col] = f2b(val);
            }
        }
    }
}

// ---------------------------------------------------------------------------
// Logits + softmax for one pooling stage (q or k). Logits via MFMA.
// su rows 8..15 are NOT zeroed: they only feed MFMA C-cols 8..15 which are
// never read (fr<8 guard below) — garbage there is harmless.
// ---------------------------------------------------------------------------
DEV void logits_stage(const u16b* __restrict__ S, const u16b* __restrict__ sv,
                      int awoff, int aboff, const float* mult,
                      const int* srow, u16b* su, float* slog, int tid) {
    // build su rows 0..7 : su[h*260 + c] = aw[c,h] (* mult[c])
    for (int i = tid; i < 2048; i += 512) {
        int c = i >> 3, h = i & 7;
        float w = sh2f(sv[awoff + i]);
        if (mult) w *= mult[c];
        su[h * 260 + c] = f2b(w);
    }
    __syncthreads();
    int wv = tid >> 6, lane = tid & 63;
    int fr = lane & 15, fq = lane >> 4;
    floatx4 acc = {0.f, 0.f, 0.f, 0.f};
    const u16b* Ar = S + (size_t)srow[wv * 16 + fr] * 256;
#pragma unroll
    for (int s = 0; s < 8; ++s) {
        short8 a  = *(const short8*)&Ar[s * 32 + fq * 8];
        short8 bb = *(const short8*)&su[fr * 260 + s * 32 + fq * 8];
        acc = __builtin_amdgcn_mfma_f32_16x16x32_bf16(a, bb, acc, 0, 0, 0);
    }
    float abv = sh2f(sv[aboff + (fr & 7)]);
    if (fr < 8) {
#pragma unroll
        for (int r = 0; r < 4; ++r)
            slog[(wv * 16 + fq * 4 + r) * 9 + fr] = (acc[r] + abv) * 0.17677669529663687f;
    }
    __syncthreads();
    // softmax over l=0..124 for head h = wv (8 waves, 8 heads)
    {
        int h = wv;
        float v0 = (lane < 125) ? slog[lane * 9 + h] : -1e30f;
        float v1 = (lane + 64 < 125) ? slog[(lane + 64) * 9 + h] : -1e30f;
        float mx = fmaxf(v0, v1);
#pragma unroll
        for (int o = 32; o; o >>= 1) mx = fmaxf(mx, __shfl_xor(mx, o));
        float e0 = (lane < 125) ? __expf(v0 - mx) : 0.f;
        float e1 = (lane + 64 < 125) ? __expf(v1 - mx) : 0.f;
        float s = e0 + e1;
#pragma unroll
        for (int o = 32; o; o >>= 1) s += __shfl_xor(s, o);
        float inv = 1.f / s;
        if (lane < 125) slog[lane * 9 + h] = e0 * inv;
        if (lane + 64 < 125) slog[(lane + 64) * 9 + h] = e1 * inv;
    }
    __syncthreads();
}

// ---------------------------------------------------------------------------
// Fused q-pool+qbar, k-pool, vbarP. One block per b=(n,t), 512 threads.
// The q window-mean (qbar) is fused into the q-pool sweep: the 125 window
// rows are loaded and converted ONCE, feeding both the plain sum (mean) and
// the softmax-weighted sum (pool).
// Writes combo rows CB[(b*25+v)*512 + {0..255 = vbarP, 256..511 = qbar}].
// ---------------------------------------------------------------------------
__global__ __launch_bounds__(512)
void pool_fused(const u16b* __restrict__ qf, const u16b* __restrict__ kf,
                const u16b* __restrict__ vf, const u16b* __restrict__ sv,
                u16b* __restrict__ CB) {
    __shared__ int srow[128];
    __shared__ u16b su[16 * 260];
    __shared__ float slog[128 * 9];
    __shared__ float spool[16 * 260];
    __shared__ float spq[256], spk[256];
    int bid = blockIdx.x;
    int b = ((bid & 7) << 8) | (bid >> 3);   // XCD-aware: bid%8 -> n-group
    int n = b >> 6, t = b & 63;
    int tid = threadIdx.x;
    if (tid < 128) {
        int l = tid < 125 ? tid : 124;
        int w = l / 25, v = l - w * 25, tt = t + w - 2;
        srow[tid] = ((unsigned)tt < 64u) ? (n * 64 + tt) * 25 + v : 51200;
    }
    __syncthreads();

    // ---- q logits + softmax -> slog weights ----
    logits_stage(qf, sv, O_QAW, O_QAB, nullptr, srow, su, slog, tid);

    // ---- fused q-pool + qbar (v-major sweep; one load+cvt per element) ----
    {
        int c8 = (tid & 31) * 8, h = c8 >> 5, ls = tid >> 5;
        float p[8] = {0.f, 0.f, 0.f, 0.f, 0.f, 0.f, 0.f, 0.f};
        for (int v = ls; v < 25; v += 16) {
            float s[8] = {0.f, 0.f, 0.f, 0.f, 0.f, 0.f, 0.f, 0.f};
#pragma unroll
            for (int w = 0; w < 5; ++w) {
                int l = w * 25 + v;
                float wt = slog[l * 9 + h];
                short8 d8 = *(const short8*)&qf[(size_t)srow[l] * 256 + c8];
#pragma unroll
                for (int j = 0; j < 8; ++j) {
                    float f = sh2f((unsigned short)d8[j]);
                    s[j] += f;
                    p[j] += wt * f;
                }
            }
            unsigned short o[8];
#pragma unroll
            for (int j = 0; j < 8; ++j) o[j] = f2b(s[j] * 0.2f);
            *(uint4*)&CB[((size_t)b * 25 + v) * 512 + 256 + c8] = *(uint4*)o;
        }
#pragma unroll
        for (int j = 0; j < 8; ++j) spool[ls * 260 + c8 + j] = p[j];
    }
    __syncthreads();
    if (tid < 256) {
        float s = 0.f;
#pragma unroll
        for (int q = 0; q < 16; ++q) s += spool[q * 260 + tid];
        spq[tid] = s;
    }
    __syncthreads();

    // ---- k logits (pq-modulated) + softmax ----
    logits_stage(kf, sv, O_KAW, O_KAB, spq, srow, su, slog, tid);

    // ---- k-pool (l-major, balanced; no mean needed) ----
    {
        int c8 = (tid & 31) * 8, h2 = c8 >> 5, ls = tid >> 5;
        float a8[8] = {0.f, 0.f, 0.f, 0.f, 0.f, 0.f, 0.f, 0.f};
        for (int l = ls; l < 125; l += 16) {
            float w = slog[l * 9 + h2];
            short8 d8 = *(const short8*)&kf[(size_t)srow[l] * 256 + c8];
#pragma unroll
            for (int j = 0; j < 8; ++j) a8[j] += w * sh2f((unsigned short)d8[j]);
        }
#pragma unroll
        for (int j = 0; j < 8; ++j) spool[ls * 260 + c8 + j] = a8[j];
    }
    __syncthreads();
    if (tid < 256) {
        float s = 0.f;
#pragma unroll
        for (int q = 0; q < 16; ++q) s += spool[q * 260 + tid];
        spk[tid] = s;
    }
    __syncthreads();

    // ---- vbarP = mean_w v * pk -> CB cols 0..255 ----
    {
        int c8 = (tid & 31) * 8, ls = tid >> 5;
        for (int v = ls; v < 25; v += 16) {
            float s[8] = {0.f, 0.f, 0.f, 0.f, 0.f, 0.f, 0.f, 0.f};
#pragma unroll
            for (int w = 0; w < 5; ++w) {
                short8 d8 = *(const short8*)&vf[(size_t)srow[w * 25 + v] * 256 + c8];
#pragma unroll
                for (int j = 0; j < 8; ++j) s[j] += sh2f((unsigned short)d8[j]);
            }
            unsigned short o[8];
#pragma unroll
            for (int j = 0; j < 8; ++j) o[j] = f2b(s[j] * 0.2f * spk[c8 + j]);
            *(uint4*)&CB[((size_t)b * 25 + v) * 512 + c8] = *(uint4*)o;
        }
    }
}

// ---------------------------------------------------------------------------
extern "C" void kernel_launch(void* const* d_in, const int* in_sizes, int n_in,
                              void* d_out, int out_size, void* d_ws, size_t ws_size,
                              hipStream_t stream) {
    (void)in_sizes; (void)n_in; (void)out_size; (void)ws_size;
    const void* x    = d_in[0];
    const void* ln1g = d_in[1];  const void* ln1b = d_in[2];
    const void* q_w  = d_in[3];  const void* q_b  = d_in[4];
    const void* qa_w = d_in[5];  const void* qa_b = d_in[6];
    const void* k_w  = d_in[7];  const void* k_b  = d_in[8];
    const void* ka_w = d_in[9];  const void* ka_b = d_in[10];
    const void* v_w  = d_in[11]; const void* v_b  = d_in[12];
    const void* t_w  = d_in[13]; const void* t_b  = d_in[14];
    const void* p_w  = d_in[15]; const void* p_b  = d_in[16];
    const void* ffng = d_in[17]; const void* ffnb = d_in[18];
    const void* w1   = d_in[19]; const void* b1   = d_in[20];
    const void* w2   = d_in[21]; const void* b2   = d_in[22];

    char* ws = (char*)d_ws;
    size_t off = 0;
    auto alloc = [&](size_t bytes) { void* p = ws + off; off += (bytes + 255) & ~(size_t)255; return p; };
    const size_t RPAD = 51328;           // 51200 valid rows + 128 pad rows
    int*    flag = (int*)alloc(256);
    u16b*   sv   = (u16b*)alloc(8192 * 2);                // packed small vectors
    u16b*   wT   = (u16b*)alloc((size_t)7 * 65536 * 2);   // qT kT vT pT tT w1T w2T
    u16b*   cW   = (u16b*)alloc((size_t)256 * 512 * 2);   // comboWt: [TP^T | p_w^T]
    u16b*   xT   = (u16b*)alloc(RPAD * 256 * 2);
    u16b*   Bq   = (u16b*)alloc(RPAD * 256 * 2);          // q_full -> h1
    u16b*   Bk   = (u16b*)alloc(RPAD * 256 * 2);
    u16b*   Bv   = (u16b*)alloc(RPAD * 256 * 2);
    u16b*   CB   = (u16b*)alloc((size_t)51200 * 512 * 2); // [vbarP | qbar]
    u16b*   att  = (u16b*)alloc((size_t)51200 * 256 * 2); // att, then y in place
    float2* st1  = (float2*)alloc(RPAD * 8);
    float2* st2  = (float2*)alloc((size_t)51200 * 8);

    u16b* pT  = wT + 3 * 65536;
    u16b* tT  = wT + 4 * 65536;
    u16b* w1T = wT + 5 * 65536;
    u16b* w2T = wT + 6 * 65536;

    // 0) dtype detection
    detect_k<<<1, 256, 0, stream>>>((const unsigned*)x, flag);
    // 1) small-vector conversion
    VecTab tab;
    const void* vp[15] = {ln1g, ln1b, q_b, k_b, v_b, t_b, p_b, ffng, ffnb, b1, b2, qa_b, ka_b, qa_w, ka_w};
    const int vo[15] = {O_LN1G, O_LN1B, O_QB, O_KB, O_VB, O_TB, O_PB, O_FFNG, O_FFNB, O_B1, O_B2, O_QAB, O_KAB, O_QAW, O_KAW};
    const int vn[15] = {256, 256, 256, 256, 256, 256, 256, 256, 256, 256, 256, 8, 8, 2048, 2048};
    for (int i = 0; i < 15; ++i) { tab.p[i] = vp[i]; tab.off[i] = vo[i]; tab.n[i] = vn[i]; }
    convert_vecs_k<<<15, 256, 0, stream>>>(tab, flag, sv);

    dim3 tb(32, 8);
    // 2) weight transposes: slices 0-6 -> wT slabs; slice 7: p_w^T -> cW cols 256.. (stride 512)
    W8 wt;
    const void* wsrc[8] = {q_w, k_w, v_w, p_w, t_w, w1, w2, p_w};
    for (int i = 0; i < 8; ++i) {
        wt.p[i] = wsrc[i];
        wt.dstoff[i] = (i < 7) ? (unsigned)(i * 65536) : (unsigned)((cW + 256) - wT);
        wt.rstride[i] = (i < 7) ? 256u : 512u;
    }
    wtrans_k<<<dim3(8, 8, 8), tb, 0, stream>>>(wt, wT, flag);
    // 3) cvec = t_b @ p_w + p_b  (into sv+O_CV)
    cvec_k<<<1, 256, 0, stream>>>(pT, sv);
    // 4) TP^T into cW cols 0..255:  out[m,k] = sum_j pT[m,j] tT[k,j] = (t_w@p_w)[k,m]
    gemm256<0, 0><<<dim3(2, 2), 256, 0, stream>>>(pT, 256, 256, tT, nullptr, nullptr,
                                                  cW, 512, nullptr, nullptr, nullptr);
    // 5) x (n, 256, 1600) -> xT (n, 1600, 256)
    transpose_in_k<<<dim3(50, 8, 32), 256, 0, stream>>>(x, xT, 256, 1600, flag);
    // 6) LN stats of xT rows (pad rows -> (0,0) => inline LN yields ln1_b)
    rowstats_k<<<12832, 256, 0, stream>>>(xT, st1, 51200, 51328);
    // 7) fused q/k/v GEMM with inline LN; tri-split out Bq/Bk/Bv
    gemm256<4, 1><<<dim3(401, 6), 256, 0, stream>>>(xT, 256, 256, wT, sv + O_QB, nullptr,
                                                    Bq, RPAD * 256, st1, sv + O_LN1G, sv + O_LN1B);
    // 8) fused pools + window means -> CB
    pool_fused<<<2048, 512, 0, stream>>>(Bq, Bk, Bv, sv, CB);
    // 9) att = CB @ comboWt^T + cvec + x_residual   (K=512)
    gemm256<2, 0><<<dim3(400, 2), 256, 0, stream>>>(CB, 512, 512, cW, sv + O_CV, xT,
                                                    att, 256, nullptr, nullptr, nullptr);
    // 10) LN stats of att rows
    rowstats_k<<<12800, 256, 0, stream>>>(att, st2, 51200, 51200);
    // 11) h1 = gelu(LN(att) @ w1 + b1) with inline LN (into Bq)
    gemm256<3, 1><<<dim3(400, 2), 256, 0, stream>>>(att, 256, 256, w1T, sv + O_B1, nullptr,
                                                    Bq, 256, st2, sv + O_FFNG, sv + O_FFNB);
    // 12) y = h1 @ w2 + b2 + att (in place into att)
    gemm256<2, 0><<<dim3(400, 2), 256, 0, stream>>>(Bq, 256, 256, w2T, sv + O_B2, att,
                                                    att, 256, nullptr, nullptr, nullptr);
    // 13) y (n, 1600, 256) -> out (n, 256, 1600)
    transpose_out_k<<<dim3(8, 50, 32), 256, 0, stream>>>(att, d_out, 1600, 256, flag);
}